// Round 7
// baseline (1895.071 us; speedup 1.0000x reference)
//
#include <hip/hip_runtime.h>
#include <hip/hip_bf16.h>
#include <cstddef>

#define HIDDEN 512
#define ATOM_FDIM 133
#define BOND_FDIM 14
#define FB_DIM 147
#define MAX_NB 6
#define BM 64
#define NT_MSG 16          // K-tiles message phase (512/32)
#define NT_ATOM 5          // K-tiles atom phase (160/32, pad of 133)

typedef __attribute__((ext_vector_type(8))) short s16x8;
typedef __attribute__((ext_vector_type(16))) unsigned char u8x16;
typedef __attribute__((ext_vector_type(4))) float f32x4;

__device__ __forceinline__ float uf(unsigned short u) {
    return __uint_as_float(((unsigned)u) << 16);
}
__device__ __forceinline__ unsigned short fb(float f) {
    __hip_bfloat16 h = __float2bfloat16(f);
    return *reinterpret_cast<unsigned short*>(&h);
}

// LDS A tile: 64 chunks(16B = 8 bf16 k-octet) x 64 rows, XOR-swizzled.
#define A_UNIT(ch, row) (((ch) << 6) + ((row) ^ ((ch) & 7)))

// ---------------------------------------------------------------------------
// One-time weight convert: f32 [Ksrc][512] -> bf16 MFMA-fragment order.
// ---------------------------------------------------------------------------
__global__ __launch_bounds__(256) void cvt_w(const float* __restrict__ src,
                                             unsigned short* __restrict__ dst,
                                             int Ksrc, int nchunks)
{
    int c = blockIdx.x * 256 + threadIdx.x;
    if (c >= nchunks) return;
    int tile = c >> 11, pc = c & 2047, n = pc >> 2, s = pc & 3;
    s16x8 o;
    #pragma unroll
    for (int e = 0; e < 8; e++) {
        int k = tile * 32 + s * 8 + e;
        float v = (k < Ksrc) ? src[(size_t)k * HIDDEN + n] : 0.f;
        o[e] = (short)fb(v);
    }
    reinterpret_cast<s16x8*>(dst)[c] = o;
}

// ---------------------------------------------------------------------------
// MFMA multi-phase GEMM. 512 thr = 8 waves (2M x 4N), BM=64 x BN=512.
// Messages live as u8 + per-row scale (gather bytes halved); dequant fused
// into A-staging.  EPI 0: first GEMM (dual-acc: Wi->acc, bond@Wh2->acc2;
// baseOut = acc+acc2, quant relu(acc)).  EPI 1: quant relu(acc+base).
// EPI 2: bf16 relu(acc+bias).
// ---------------------------------------------------------------------------
template<int EPI, bool P0, bool P1, bool P2>
__global__ __launch_bounds__(512, (EPI == 0) ? 2 : 4) void mfma_gemm(
    const unsigned char* __restrict__ msgq, const float* __restrict__ mscale,
    const int* __restrict__ a2a, const unsigned short* __restrict__ Wm,
    const float* __restrict__ atomf, const unsigned short* __restrict__ Wa,
    const float* __restrict__ fbonds, const int* __restrict__ a2b,
    const unsigned short* __restrict__ Wb,
    const unsigned short* __restrict__ base, const float* __restrict__ bias,
    unsigned short* __restrict__ outv, unsigned short* __restrict__ baseOut,
    unsigned char* __restrict__ qout, float* __restrict__ qscale,
    int M)
{
    __shared__ s16x8 As[64 * 64];                    // 64 KB
    __shared__ float rmax[BM][4];

    const int t    = threadIdx.x;
    const int m0   = blockIdx.x * BM;
    const int lane = t & 63;
    const int l15  = lane & 15, lhi = lane >> 4;
    const int w    = t >> 6, wm = w >> 2, wn = w & 3;
    const int rs   = t >> 3, oc = t & 7;             // staging: row, octet

    int srow = m0 + rs; if (srow >= M) srow = M - 1;

    f32x4 acc[2][8];
    #pragma unroll
    for (int mr = 0; mr < 2; mr++)
        #pragma unroll
        for (int nr = 0; nr < 8; nr++)
            acc[mr][nr] = (f32x4){0.f, 0.f, 0.f, 0.f};
    f32x4 acc2[2][8];
    if (EPI == 0) {
        #pragma unroll
        for (int mr = 0; mr < 2; mr++)
            #pragma unroll
            for (int nr = 0; nr < 8; nr++)
                acc2[mr][nr] = (f32x4){0.f, 0.f, 0.f, 0.f};
    }

#define LOADB(B_, WT, TILE) do {                                              \
    const s16x8* bb_ = reinterpret_cast<const s16x8*>(                        \
        (WT) + (size_t)(TILE) * (HIDDEN * 32)) + ((wn * 128 + l15) * 4 + lhi);\
    _Pragma("unroll")                                                         \
    for (int nr_ = 0; nr_ < 8; nr_++) B_[nr_] = bb_[nr_ * 64];                \
} while (0)

#define TILE_MFMA(TILE, B_, ACC) do {                                         \
    s16x8 a0_ = As[A_UNIT((TILE) * 4 + lhi, wm * 32 + l15)];                  \
    s16x8 a1_ = As[A_UNIT((TILE) * 4 + lhi, wm * 32 + 16 + l15)];             \
    __builtin_amdgcn_s_setprio(1);                                            \
    _Pragma("unroll")                                                         \
    for (int nr_ = 0; nr_ < 8; nr_++) {                                       \
        ACC[0][nr_] = __builtin_amdgcn_mfma_f32_16x16x32_bf16(a0_, B_[nr_], ACC[0][nr_], 0, 0, 0); \
        ACC[1][nr_] = __builtin_amdgcn_mfma_f32_16x16x32_bf16(a1_, B_[nr_], ACC[1][nr_], 0, 0, 0); \
    }                                                                         \
    __builtin_amdgcn_s_setprio(0);                                            \
} while (0)

#define PHASE(WT, NT, ACC) do {                                               \
    s16x8 b0_[8], b1_[8];                                                     \
    LOADB(b0_, WT, 0);                                                        \
    _Pragma("unroll")                                                         \
    for (int tp_ = 0; tp_ < (NT) / 2; ++tp_) {                                \
        LOADB(b1_, WT, 2 * tp_ + 1);                                          \
        TILE_MFMA(2 * tp_, b0_, ACC);                                         \
        if (2 * tp_ + 2 < (NT)) LOADB(b0_, WT, 2 * tp_ + 2);                  \
        TILE_MFMA(2 * tp_ + 1, b1_, ACC);                                     \
    }                                                                         \
    if ((NT) & 1) TILE_MFMA((NT) - 1, b0_, ACC);                              \
} while (0)

    // ---- P0: gathered u8 message, K = 512, one-shot staged + dequant ----
    if (P0) {
        const unsigned char* pA[MAX_NB];
        float sc[MAX_NB];
        #pragma unroll
        for (int j = 0; j < MAX_NB; j++) {
            int idx = a2a[(size_t)srow * MAX_NB + j];
            pA[j] = msgq + (size_t)idx * HIDDEN;
            sc[j] = mscale[idx];
        }
        s16x8 b0_[8], b1_[8];
        LOADB(b0_, Wm, 0);                 // B tile 0 in flight during staging
        u8x16 v0[MAX_NB], v1[MAX_NB];
        #pragma unroll
        for (int j = 0; j < MAX_NB; j++)
            v0[j] = *reinterpret_cast<const u8x16*>(pA[j] + oc * 16);

#define GROUND(CUR, NXT, R) do {                                              \
    if ((R) < 3) {                                                            \
        _Pragma("unroll")                                                     \
        for (int j = 0; j < MAX_NB; j++)                                      \
            NXT[j] = *reinterpret_cast<const u8x16*>(pA[j] + ((R) + 1) * 128 + oc * 16); \
    }                                                                         \
    __builtin_amdgcn_sched_barrier(0);                                        \
    float s_[16];                                                             \
    _Pragma("unroll") for (int e = 0; e < 16; e++) s_[e] = 0.f;               \
    _Pragma("unroll")                                                         \
    for (int j = 0; j < MAX_NB; j++)                                          \
        _Pragma("unroll")                                                     \
        for (int e = 0; e < 16; e++) s_[e] += sc[j] * (float)CUR[j][e];       \
    s16x8 o0_, o1_;                                                           \
    _Pragma("unroll")                                                         \
    for (int e = 0; e < 8; e++) { o0_[e] = (short)fb(s_[e]); o1_[e] = (short)fb(s_[e + 8]); } \
    int ch_ = (R) * 16 + oc * 2;                                              \
    As[A_UNIT(ch_, rs)]     = o0_;                                            \
    As[A_UNIT(ch_ + 1, rs)] = o1_;                                            \
} while (0)

        GROUND(v0, v1, 0);
        GROUND(v1, v0, 1);
        GROUND(v0, v1, 2);
        GROUND(v1, v0, 3);
#undef GROUND
        __syncthreads();
        #pragma unroll
        for (int tp = 0; tp < NT_MSG / 2; ++tp) {
            LOADB(b1_, Wm, 2 * tp + 1);
            TILE_MFMA(2 * tp, b0_, acc);
            if (2 * tp + 2 < NT_MSG) LOADB(b0_, Wm, 2 * tp + 2);
            TILE_MFMA(2 * tp + 1, b1_, acc);
        }
    }

    // ---- P1: direct atom features, K = 160 (pad of 133) ----
    if (P1) {
        if (P0) __syncthreads();
        {
            int grow = m0 + rs;
            bool ok = grow < M;
            #pragma unroll
            for (int c8 = 0; c8 < 3; ++c8) {
                int ch = c8 * 8 + oc;
                s16x8 o;
                #pragma unroll
                for (int e = 0; e < 8; e++) {
                    int k = ch * 8 + e;
                    float v = (ok && k < ATOM_FDIM)
                                  ? atomf[(size_t)grow * ATOM_FDIM + k] : 0.f;
                    o[e] = (short)fb(v);
                }
                As[A_UNIT(ch, rs)] = o;
            }
        }
        __syncthreads();
        PHASE(Wa, NT_ATOM, acc);
    }

    // ---- P2: gathered bond features, K = 32 (pad of 14) ----
    if (P2) {
        __syncthreads();
        if (oc < 4) {
            int ch = oc;
            float s[8] = {0.f,0.f,0.f,0.f,0.f,0.f,0.f,0.f};
            #pragma unroll
            for (int j = 0; j < MAX_NB; j++) {
                int b = a2b[(size_t)srow * MAX_NB + j];
                #pragma unroll
                for (int e = 0; e < 8; e++) {
                    int k = ch * 8 + e;
                    if (k < BOND_FDIM) s[e] += fbonds[(size_t)b * FB_DIM + ATOM_FDIM + k];
                }
            }
            s16x8 o;
            #pragma unroll
            for (int e = 0; e < 8; e++) o[e] = (short)fb(s[e]);
            As[A_UNIT(ch, rs)] = o;
        }
        __syncthreads();
        if (EPI == 0) { PHASE(Wb, 1, acc2); }
        else          { PHASE(Wb, 1, acc); }
    }

    // ======================= epilogues =======================
    if (EPI == 2) {
        #pragma unroll
        for (int mr = 0; mr < 2; mr++)
            #pragma unroll
            for (int nr = 0; nr < 8; nr++) {
                int col = wn * 128 + nr * 16 + l15;
                #pragma unroll
                for (int rg = 0; rg < 4; rg++) {
                    int row = m0 + wm * 32 + mr * 16 + lhi * 4 + rg;
                    if (row >= M) continue;
                    outv[(size_t)row * HIDDEN + col] =
                        fb(fmaxf(acc[mr][nr][rg] + bias[col], 0.f));
                }
            }
        return;
    }

    // EPI 0/1: fold base / relu into acc, then row-quantize to u8.
    if (EPI == 0) {
        #pragma unroll
        for (int mr = 0; mr < 2; mr++)
            #pragma unroll
            for (int nr = 0; nr < 8; nr++) {
                int col = wn * 128 + nr * 16 + l15;
                #pragma unroll
                for (int rg = 0; rg < 4; rg++) {
                    int row = m0 + wm * 32 + mr * 16 + lhi * 4 + rg;
                    if (row < M)
                        baseOut[(size_t)row * HIDDEN + col] =
                            fb(acc[mr][nr][rg] + acc2[mr][nr][rg]);
                    acc[mr][nr][rg] = fmaxf(acc[mr][nr][rg], 0.f);
                }
            }
    } else {
        #pragma unroll
        for (int mr = 0; mr < 2; mr++)
            #pragma unroll
            for (int nr = 0; nr < 8; nr++) {
                int col = wn * 128 + nr * 16 + l15;
                #pragma unroll
                for (int rg = 0; rg < 4; rg++) {
                    int row = m0 + wm * 32 + mr * 16 + lhi * 4 + rg;
                    int crow = (row < M) ? row : (M - 1);
                    acc[mr][nr][rg] =
                        fmaxf(acc[mr][nr][rg] + uf(base[(size_t)crow * HIDDEN + col]), 0.f);
                }
            }
    }

    // per-row max: 8 cols/lane -> 128 cols/wave (shfl over l15) -> LDS x4 waves
    #pragma unroll
    for (int mr = 0; mr < 2; mr++)
        #pragma unroll
        for (int rg = 0; rg < 4; rg++) {
            float pm = acc[mr][0][rg];
            #pragma unroll
            for (int nr = 1; nr < 8; nr++) pm = fmaxf(pm, acc[mr][nr][rg]);
            pm = fmaxf(pm, __shfl_xor(pm, 1));
            pm = fmaxf(pm, __shfl_xor(pm, 2));
            pm = fmaxf(pm, __shfl_xor(pm, 4));
            pm = fmaxf(pm, __shfl_xor(pm, 8));
            if (l15 == 0) rmax[wm * 32 + mr * 16 + lhi * 4 + rg][wn] = pm;
        }
    __syncthreads();   // also guards As reuse as u8 buffer below

    unsigned char* qb = reinterpret_cast<unsigned char*>(As);
    #pragma unroll
    for (int mr = 0; mr < 2; mr++)
        #pragma unroll
        for (int rg = 0; rg < 4; rg++) {
            int lrow = wm * 32 + mr * 16 + lhi * 4 + rg;
            float m4 = fmaxf(fmaxf(rmax[lrow][0], rmax[lrow][1]),
                             fmaxf(rmax[lrow][2], rmax[lrow][3]));
            float inv = (m4 > 0.f) ? 255.f / m4 : 0.f;
            #pragma unroll
            for (int nr = 0; nr < 8; nr++) {
                int col = wn * 128 + nr * 16 + l15;
                qb[lrow * HIDDEN + col] =
                    (unsigned char)(acc[mr][nr][rg] * inv + 0.5f);
            }
        }
    __syncthreads();

    {
        int grow = m0 + rs;
        if (grow < M) {
            #pragma unroll
            for (int i = 0; i < 4; i++) {
                u8x16 vq = *reinterpret_cast<const u8x16*>(
                    &qb[rs * HIDDEN + oc * 64 + i * 16]);
                *reinterpret_cast<u8x16*>(
                    &qout[(size_t)grow * HIDDEN + oc * 64 + i * 16]) = vq;
            }
            if (oc == 0) {
                float m4 = fmaxf(fmaxf(rmax[rs][0], rmax[rs][1]),
                                 fmaxf(rmax[rs][2], rmax[rs][3]));
                qscale[grow] = (m4 > 0.f) ? m4 / 255.f : 0.f;
            }
        }
    }
#undef PHASE
#undef TILE_MFMA
#undef LOADB
}

// ---------------------------------------------------------------------------
// Per-molecule segment mean + counts (+ fused nz from atomf row-sums).
// ---------------------------------------------------------------------------
__global__ __launch_bounds__(512) void seg_k(const unsigned short* __restrict__ hid,
                                             const float* __restrict__ atomf,
                                             const int*   __restrict__ mol_ids,
                                             float* __restrict__ out, int M, int NM)
{
    int m = blockIdx.x;
    int t = threadIdx.x;
    int lo = 0, hi = M;
    while (lo < hi) { int mid = (lo + hi) >> 1; if (mol_ids[mid] < m) lo = mid + 1; else hi = mid; }
    int s = lo;
    lo = 0; hi = M;
    while (lo < hi) { int mid = (lo + hi) >> 1; if (mol_ids[mid] < m + 1) lo = mid + 1; else hi = mid; }
    int e = lo;

    float acc = 0.f;
    for (int a = s; a < e; a++) acc += uf(hid[(size_t)a * HIDDEN + t]);

    float nzp = 0.f;
    for (int a = s + t; a < e; a += 512) {
        const float* r = atomf + (size_t)a * ATOM_FDIM;
        float ss = 0.f;
        #pragma unroll 7
        for (int c = 0; c < ATOM_FDIM; c++) ss += r[c];
        nzp += (ss > 0.f) ? 1.f : 0.f;
    }
    __shared__ float red[512];
    red[t] = nzp; __syncthreads();
    for (int off = 256; off; off >>= 1) { if (t < off) red[t] += red[t + off]; __syncthreads(); }

    int cnt = e - s;
    float inv = 1.f / fmaxf((float)cnt, 1.f);
    out[(size_t)m * HIDDEN + t] = acc * inv;
    if (t == 0) {
        out[(size_t)NM * HIDDEN + 2 * m]     = red[0];
        out[(size_t)NM * HIDDEN + 2 * m + 1] = (float)cnt;
    }
}

// ---------------------------------------------------------------------------
extern "C" void kernel_launch(void* const* d_in, const int* in_sizes, int n_in,
                              void* d_out, int out_size, void* d_ws, size_t ws_size,
                              hipStream_t stream)
{
    const float* atomf   = (const float*)d_in[0];
    const float* f_bonds = (const float*)d_in[1];
    const int*   a2a     = (const int*)d_in[2];
    const int*   a2b     = (const int*)d_in[3];
    const int*   mol_ids = (const int*)d_in[4];
    const float* W_i     = (const float*)d_in[5];
    const float* W_h     = (const float*)d_in[6];
    const float* W_o     = (const float*)d_in[7];
    const float* b_o     = (const float*)d_in[8];
    float* out = (float*)d_out;

    const int M  = in_sizes[2] / MAX_NB;   // 100000
    const int NM = 1000;
    const size_t SZ = (size_t)M * HIDDEN;

    // ---- workspace layout ----
    const size_t TCH = HIDDEN * 32;                 // ushorts per tile
    unsigned short* WiT  = (unsigned short*)d_ws;
    unsigned short* Wh1T = WiT  + 5  * TCH;
    unsigned short* Wh2T = Wh1T + 16 * TCH;
    unsigned short* Wo1T = Wh2T + 1  * TCH;
    unsigned short* Wo2T = Wo1T + 5  * TCH;
    char* p = (char*)(Wo2T + 16 * TCH);
    unsigned short* baseB = (unsigned short*)p; p += SZ * 2;   // bf16 base / hid
    unsigned char*  msgQA = (unsigned char*)p;  p += SZ;       // u8 messages
    unsigned char*  msgQB = (unsigned char*)p;  p += SZ;
    float* scaleA = (float*)p; p += (size_t)M * 4;
    float* scaleB = (float*)p;

    const int gG = (M + BM - 1) / BM;

    // ---- weight conversion (fragment-ordered bf16 tiles) ----
    cvt_w<<<(5  * 2048 + 255) / 256, 256, 0, stream>>>(W_i,  WiT,  ATOM_FDIM, 5  * 2048);
    cvt_w<<<(16 * 2048 + 255) / 256, 256, 0, stream>>>(W_h,  Wh1T, HIDDEN,    16 * 2048);
    cvt_w<<<(1  * 2048 + 255) / 256, 256, 0, stream>>>(W_h + (size_t)HIDDEN * HIDDEN,
                                                       Wh2T, BOND_FDIM, 1 * 2048);
    cvt_w<<<(5  * 2048 + 255) / 256, 256, 0, stream>>>(W_o,  Wo1T, ATOM_FDIM, 5  * 2048);
    cvt_w<<<(16 * 2048 + 255) / 256, 256, 0, stream>>>(W_o + (size_t)ATOM_FDIM * HIDDEN,
                                                       Wo2T, HIDDEN, 16 * 2048);

    // first GEMM: acc=atomf@Wi, acc2=bond@Wh2; msgQA=quant(relu(acc)),
    // baseB = acc + acc2  (write-only)
    mfma_gemm<0, false, true, true><<<gG, 512, 0, stream>>>(
        nullptr, nullptr, nullptr, nullptr, atomf, WiT, f_bonds, a2b, Wh2T,
        nullptr, nullptr, nullptr, baseB, msgQA, scaleA, M);
    // 3 iters: msg' = quant(relu(g6(msg)@Wh1 + base))
    mfma_gemm<1, true, false, false><<<gG, 512, 0, stream>>>(
        msgQA, scaleA, a2a, Wh1T, nullptr, nullptr, nullptr, nullptr, nullptr,
        baseB, nullptr, nullptr, nullptr, msgQB, scaleB, M);
    mfma_gemm<1, true, false, false><<<gG, 512, 0, stream>>>(
        msgQB, scaleB, a2a, Wh1T, nullptr, nullptr, nullptr, nullptr, nullptr,
        baseB, nullptr, nullptr, nullptr, msgQA, scaleA, M);
    mfma_gemm<1, true, false, false><<<gG, 512, 0, stream>>>(
        msgQA, scaleA, a2a, Wh1T, nullptr, nullptr, nullptr, nullptr, nullptr,
        baseB, nullptr, nullptr, nullptr, msgQB, scaleB, M);
    // hid = relu(g6(msgQB)@Wo2 + atomf@Wo1 + b_o) -> baseB (bf16, reuse)
    mfma_gemm<2, true, true, false><<<gG, 512, 0, stream>>>(
        msgQB, scaleB, a2a, Wo2T, atomf, Wo1T, nullptr, nullptr, nullptr,
        nullptr, b_o, baseB, nullptr, nullptr, nullptr, M);
    // segment mean + counts (+ fused nz)
    seg_k<<<NM, 512, 0, stream>>>(baseB, atomf, mol_ids, out, M, NM);
}

// Round 8
// 1158.217 us; speedup vs baseline: 1.6362x; 1.6362x over previous
//
#include <hip/hip_runtime.h>
#include <hip/hip_bf16.h>
#include <cstddef>

#define HIDDEN 512
#define ATOM_FDIM 133
#define BOND_FDIM 14
#define FB_DIM 147
#define MAX_NB 6
#define BM 64
#define NT_MSG 16          // K-tiles message phase (512/32)
#define NT_ATOM 5          // K-tiles atom phase (160/32, pad of 133)

typedef __attribute__((ext_vector_type(8))) short s16x8;
typedef __attribute__((ext_vector_type(16))) unsigned char u8x16;
typedef __attribute__((ext_vector_type(4))) float f32x4;

__device__ __forceinline__ float uf(unsigned short u) {
    return __uint_as_float(((unsigned)u) << 16);
}
__device__ __forceinline__ unsigned short fb(float f) {
    __hip_bfloat16 h = __float2bfloat16(f);
    return *reinterpret_cast<unsigned short*>(&h);
}

// LDS A tile: 64 chunks(16B = 8 bf16 k-octet) x 64 rows, XOR-swizzled.
#define A_UNIT(ch, row) (((ch) << 6) + ((row) ^ ((ch) & 7)))

// ---------------------------------------------------------------------------
// One-time weight convert: f32 [Ksrc][512] -> bf16 MFMA-fragment order.
// ---------------------------------------------------------------------------
__global__ __launch_bounds__(256) void cvt_w(const float* __restrict__ src,
                                             unsigned short* __restrict__ dst,
                                             int Ksrc, int nchunks)
{
    int c = blockIdx.x * 256 + threadIdx.x;
    if (c >= nchunks) return;
    int tile = c >> 11, pc = c & 2047, n = pc >> 2, s = pc & 3;
    s16x8 o;
    #pragma unroll
    for (int e = 0; e < 8; e++) {
        int k = tile * 32 + s * 8 + e;
        float v = (k < Ksrc) ? src[(size_t)k * HIDDEN + n] : 0.f;
        o[e] = (short)fb(v);
    }
    reinterpret_cast<s16x8*>(dst)[c] = o;
}

// ---------------------------------------------------------------------------
// MFMA GEMM, 512 thr = 8 waves (2M x 4N), BM=64 x BN=512.  Messages are u8
// with per-row scale (gather bytes halved); dequant fused into A-staging.
// Register discipline: single-buffered staging (v[6]) and B loads (b[8]),
// u32 gather offsets -> fits the 128-reg/wave budget of launch_bounds(512,4)
// (64 arch + 64 AGPR acc) without scratch spills.
// EPI 0: baseOut += acc (bf16 RMW); quant(relu(acc)) -> qout.
// EPI 1: quant(relu(acc + base)) -> qout.
// EPI 2: outv = bf16 relu(acc + bias).
// ---------------------------------------------------------------------------
template<int EPI, bool P0, bool P1>
__global__ __launch_bounds__(512, 4) void mfma_gemm(
    const unsigned char* __restrict__ msgq, const float* __restrict__ mscale,
    const int* __restrict__ a2a, const unsigned short* __restrict__ Wm,
    const float* __restrict__ atomf, const unsigned short* __restrict__ Wa,
    const unsigned short* __restrict__ base, const float* __restrict__ bias,
    unsigned short* __restrict__ outv, unsigned short* __restrict__ baseOut,
    unsigned char* __restrict__ qout, float* __restrict__ qscale,
    int M)
{
    __shared__ s16x8 As[64 * 64];                    // 64 KB
    __shared__ float rmax[BM][4];

    const int t    = threadIdx.x;
    const int m0   = blockIdx.x * BM;
    const int lane = t & 63;
    const int l15  = lane & 15, lhi = lane >> 4;
    const int w    = t >> 6, wm = w >> 2, wn = w & 3;
    const int rs   = t >> 3, oc = t & 7;             // staging: row, octet

    int srow = m0 + rs; if (srow >= M) srow = M - 1;

    f32x4 acc[2][8];
    #pragma unroll
    for (int mr = 0; mr < 2; mr++)
        #pragma unroll
        for (int nr = 0; nr < 8; nr++)
            acc[mr][nr] = (f32x4){0.f, 0.f, 0.f, 0.f};

#define LOADB(B_, WT, TILE) do {                                              \
    const s16x8* bb_ = reinterpret_cast<const s16x8*>(                        \
        (WT) + (size_t)(TILE) * (HIDDEN * 32)) + ((wn * 128 + l15) * 4 + lhi);\
    _Pragma("unroll")                                                         \
    for (int nr_ = 0; nr_ < 8; nr_++) B_[nr_] = bb_[nr_ * 64];                \
} while (0)

#define TILE_MFMA(TILE, B_) do {                                              \
    s16x8 a0_ = As[A_UNIT((TILE) * 4 + lhi, wm * 32 + l15)];                  \
    s16x8 a1_ = As[A_UNIT((TILE) * 4 + lhi, wm * 32 + 16 + l15)];             \
    _Pragma("unroll")                                                         \
    for (int nr_ = 0; nr_ < 8; nr_++) {                                       \
        acc[0][nr_] = __builtin_amdgcn_mfma_f32_16x16x32_bf16(a0_, B_[nr_], acc[0][nr_], 0, 0, 0); \
        acc[1][nr_] = __builtin_amdgcn_mfma_f32_16x16x32_bf16(a1_, B_[nr_], acc[1][nr_], 0, 0, 0); \
    }                                                                         \
} while (0)

#define PHASE(WT, NT) do {                                                    \
    s16x8 b_[8];                                                              \
    _Pragma("unroll 1")                                                       \
    for (int tp_ = 0; tp_ < (NT); ++tp_) {                                    \
        LOADB(b_, WT, tp_);                                                   \
        TILE_MFMA(tp_, b_);                                                   \
    }                                                                         \
} while (0)

    // ---- P0: gathered u8 message, K = 512, one-shot staged + dequant ----
    if (P0) {
        unsigned off[MAX_NB];
        float sc[MAX_NB];
        #pragma unroll
        for (int j = 0; j < MAX_NB; j++) {
            int idx = a2a[(size_t)srow * MAX_NB + j];
            off[j] = (unsigned)idx * HIDDEN + oc * 16;
            sc[j]  = mscale[idx];
        }
        #pragma unroll
        for (int r = 0; r < 4; ++r) {
            u8x16 v[MAX_NB];
            #pragma unroll
            for (int j = 0; j < MAX_NB; j++)
                v[j] = *reinterpret_cast<const u8x16*>(msgq + off[j] + r * 128);
            float s_[16];
            #pragma unroll
            for (int e = 0; e < 16; e++) s_[e] = 0.f;
            #pragma unroll
            for (int j = 0; j < MAX_NB; j++)
                #pragma unroll
                for (int e = 0; e < 16; e++) s_[e] += sc[j] * (float)v[j][e];
            s16x8 o0, o1;
            #pragma unroll
            for (int e = 0; e < 8; e++) {
                o0[e] = (short)fb(s_[e]);
                o1[e] = (short)fb(s_[e + 8]);
            }
            int ch = r * 16 + oc * 2;
            As[A_UNIT(ch, rs)]     = o0;
            As[A_UNIT(ch + 1, rs)] = o1;
        }
        __syncthreads();
        PHASE(Wm, NT_MSG);
    }

    // ---- P1: direct atom features, K = 160 (pad of 133) ----
    if (P1) {
        if (P0) __syncthreads();
        {
            int grow = m0 + rs;
            bool ok = grow < M;
            #pragma unroll
            for (int c8 = 0; c8 < 3; ++c8) {
                int ch = c8 * 8 + oc;
                s16x8 o;
                #pragma unroll
                for (int e = 0; e < 8; e++) {
                    int k = ch * 8 + e;
                    float v = (ok && k < ATOM_FDIM)
                                  ? atomf[(size_t)grow * ATOM_FDIM + k] : 0.f;
                    o[e] = (short)fb(v);
                }
                As[A_UNIT(ch, rs)] = o;
            }
        }
        __syncthreads();
        PHASE(Wa, NT_ATOM);
    }

    // ======================= epilogues =======================
    if (EPI == 2) {
        #pragma unroll
        for (int mr = 0; mr < 2; mr++)
            #pragma unroll
            for (int nr = 0; nr < 8; nr++) {
                int col = wn * 128 + nr * 16 + l15;
                #pragma unroll
                for (int rg = 0; rg < 4; rg++) {
                    int row = m0 + wm * 32 + mr * 16 + lhi * 4 + rg;
                    if (row >= M) continue;
                    outv[(size_t)row * HIDDEN + col] =
                        fb(fmaxf(acc[mr][nr][rg] + bias[col], 0.f));
                }
            }
        return;
    }

    // EPI 0/1: fold base / relu into acc, then row-quantize to u8.
    if (EPI == 0) {
        #pragma unroll
        for (int mr = 0; mr < 2; mr++)
            #pragma unroll
            for (int nr = 0; nr < 8; nr++) {
                int col = wn * 128 + nr * 16 + l15;
                #pragma unroll
                for (int rg = 0; rg < 4; rg++) {
                    int row = m0 + wm * 32 + mr * 16 + lhi * 4 + rg;
                    if (row < M) {
                        size_t idx = (size_t)row * HIDDEN + col;
                        baseOut[idx] = fb(acc[mr][nr][rg] + uf(baseOut[idx]));
                    }
                    acc[mr][nr][rg] = fmaxf(acc[mr][nr][rg], 0.f);
                }
            }
    } else {
        #pragma unroll
        for (int mr = 0; mr < 2; mr++)
            #pragma unroll
            for (int nr = 0; nr < 8; nr++) {
                int col = wn * 128 + nr * 16 + l15;
                #pragma unroll
                for (int rg = 0; rg < 4; rg++) {
                    int row = m0 + wm * 32 + mr * 16 + lhi * 4 + rg;
                    int crow = (row < M) ? row : (M - 1);
                    acc[mr][nr][rg] =
                        fmaxf(acc[mr][nr][rg] + uf(base[(size_t)crow * HIDDEN + col]), 0.f);
                }
            }
    }

    // per-row max: 8 cols/lane -> 128 cols/wave (shfl over l15) -> LDS x4 waves
    #pragma unroll
    for (int mr = 0; mr < 2; mr++)
        #pragma unroll
        for (int rg = 0; rg < 4; rg++) {
            float pm = acc[mr][0][rg];
            #pragma unroll
            for (int nr = 1; nr < 8; nr++) pm = fmaxf(pm, acc[mr][nr][rg]);
            pm = fmaxf(pm, __shfl_xor(pm, 1));
            pm = fmaxf(pm, __shfl_xor(pm, 2));
            pm = fmaxf(pm, __shfl_xor(pm, 4));
            pm = fmaxf(pm, __shfl_xor(pm, 8));
            if (l15 == 0) rmax[wm * 32 + mr * 16 + lhi * 4 + rg][wn] = pm;
        }
    __syncthreads();   // all MFMA reads of As done; safe to reuse As below

    unsigned char* qb = reinterpret_cast<unsigned char*>(As);
    #pragma unroll
    for (int mr = 0; mr < 2; mr++)
        #pragma unroll
        for (int rg = 0; rg < 4; rg++) {
            int lrow = wm * 32 + mr * 16 + lhi * 4 + rg;
            float m4 = fmaxf(fmaxf(rmax[lrow][0], rmax[lrow][1]),
                             fmaxf(rmax[lrow][2], rmax[lrow][3]));
            float inv = (m4 > 0.f) ? 255.f / m4 : 0.f;
            #pragma unroll
            for (int nr = 0; nr < 8; nr++) {
                int col = wn * 128 + nr * 16 + l15;
                qb[lrow * HIDDEN + col] =
                    (unsigned char)(acc[mr][nr][rg] * inv + 0.5f);
            }
        }
    __syncthreads();

    {
        int grow = m0 + rs;
        if (grow < M) {
            #pragma unroll
            for (int i = 0; i < 4; i++) {
                u8x16 vq = *reinterpret_cast<const u8x16*>(
                    &qb[rs * HIDDEN + oc * 64 + i * 16]);
                *reinterpret_cast<u8x16*>(
                    &qout[(size_t)grow * HIDDEN + oc * 64 + i * 16]) = vq;
            }
            if (oc == 0) {
                float m4 = fmaxf(fmaxf(rmax[rs][0], rmax[rs][1]),
                                 fmaxf(rmax[rs][2], rmax[rs][3]));
                qscale[grow] = (m4 > 0.f) ? m4 / 255.f : 0.f;
            }
        }
    }
#undef PHASE
#undef TILE_MFMA
#undef LOADB
}

// ---------------------------------------------------------------------------
// c_b[i] = (sum_j f_bonds[a2b[i][j]][133:147]) @ W_h[512:526] -> bf16
// ---------------------------------------------------------------------------
__global__ __launch_bounds__(256) void cb_k(const float* __restrict__ f_bonds,
                                            const int*   __restrict__ a2b,
                                            const float* __restrict__ Wh2,
                                            unsigned short* __restrict__ cb, int M)
{
    int atom = blockIdx.x * 4 + (threadIdx.x >> 6);
    int lane = threadIdx.x & 63;
    if (atom >= M) return;
    int bidx = (lane < MAX_NB) ? a2b[(size_t)atom * MAX_NB + lane] : 0;
    float nb = 0.f;
    if (lane < BOND_FDIM) {
        #pragma unroll
        for (int j = 0; j < MAX_NB; j++) {
            int b = __shfl(bidx, j);
            nb += f_bonds[(size_t)b * FB_DIM + ATOM_FDIM + lane];
        }
    }
    float acc[8];
    #pragma unroll
    for (int ci = 0; ci < 8; ci++) acc[ci] = 0.f;
    #pragma unroll
    for (int k = 0; k < BOND_FDIM; k++) {
        float nbk = __shfl(nb, k);
        #pragma unroll
        for (int ci = 0; ci < 8; ci++)
            acc[ci] += nbk * Wh2[(size_t)k * HIDDEN + lane + (ci << 6)];
    }
    size_t rb = (size_t)atom * HIDDEN;
    #pragma unroll
    for (int ci = 0; ci < 8; ci++) cb[rb + lane + (ci << 6)] = fb(acc[ci]);
}

// ---------------------------------------------------------------------------
// Per-molecule segment mean + counts (+ fused nz from atomf row-sums).
// ---------------------------------------------------------------------------
__global__ __launch_bounds__(512) void seg_k(const unsigned short* __restrict__ hid,
                                             const float* __restrict__ atomf,
                                             const int*   __restrict__ mol_ids,
                                             float* __restrict__ out, int M, int NM)
{
    int m = blockIdx.x;
    int t = threadIdx.x;
    int lo = 0, hi = M;
    while (lo < hi) { int mid = (lo + hi) >> 1; if (mol_ids[mid] < m) lo = mid + 1; else hi = mid; }
    int s = lo;
    lo = 0; hi = M;
    while (lo < hi) { int mid = (lo + hi) >> 1; if (mol_ids[mid] < m + 1) lo = mid + 1; else hi = mid; }
    int e = lo;

    float acc = 0.f;
    for (int a = s; a < e; a++) acc += uf(hid[(size_t)a * HIDDEN + t]);

    float nzp = 0.f;
    for (int a = s + t; a < e; a += 512) {
        const float* r = atomf + (size_t)a * ATOM_FDIM;
        float ss = 0.f;
        #pragma unroll 7
        for (int c = 0; c < ATOM_FDIM; c++) ss += r[c];
        nzp += (ss > 0.f) ? 1.f : 0.f;
    }
    __shared__ float red[512];
    red[t] = nzp; __syncthreads();
    for (int off = 256; off; off >>= 1) { if (t < off) red[t] += red[t + off]; __syncthreads(); }

    int cnt = e - s;
    float inv = 1.f / fmaxf((float)cnt, 1.f);
    out[(size_t)m * HIDDEN + t] = acc * inv;
    if (t == 0) {
        out[(size_t)NM * HIDDEN + 2 * m]     = red[0];
        out[(size_t)NM * HIDDEN + 2 * m + 1] = (float)cnt;
    }
}

// ---------------------------------------------------------------------------
extern "C" void kernel_launch(void* const* d_in, const int* in_sizes, int n_in,
                              void* d_out, int out_size, void* d_ws, size_t ws_size,
                              hipStream_t stream)
{
    const float* atomf   = (const float*)d_in[0];
    const float* f_bonds = (const float*)d_in[1];
    const int*   a2a     = (const int*)d_in[2];
    const int*   a2b     = (const int*)d_in[3];
    const int*   mol_ids = (const int*)d_in[4];
    const float* W_i     = (const float*)d_in[5];
    const float* W_h     = (const float*)d_in[6];
    const float* W_o     = (const float*)d_in[7];
    const float* b_o     = (const float*)d_in[8];
    float* out = (float*)d_out;

    const int M  = in_sizes[2] / MAX_NB;   // 100000
    const int NM = 1000;
    const size_t SZ = (size_t)M * HIDDEN;

    const float* Wh2f = W_h + (size_t)HIDDEN * HIDDEN;

    // ---- workspace layout ----
    const size_t TCH = HIDDEN * 32;                 // ushorts per tile
    unsigned short* WiT  = (unsigned short*)d_ws;
    unsigned short* Wh1T = WiT  + 5  * TCH;
    unsigned short* Wo1T = Wh1T + 16 * TCH;
    unsigned short* Wo2T = Wo1T + 5  * TCH;
    char* p = (char*)(Wo2T + 16 * TCH);             // 42 tiles = 1.38 MB
    unsigned short* baseB = (unsigned short*)p; p += SZ * 2;   // bf16 base / hid
    unsigned char*  msgQA = (unsigned char*)p;  p += SZ;       // u8 messages
    unsigned char*  msgQB = (unsigned char*)p;  p += SZ;
    float* scaleA = (float*)p; p += (size_t)M * 4;
    float* scaleB = (float*)p;

    const int gA = (M + 3) / 4;
    const int gG = (M + BM - 1) / BM;

    // ---- weight conversion (fragment-ordered bf16 tiles) ----
    cvt_w<<<(5  * 2048 + 255) / 256, 256, 0, stream>>>(W_i,  WiT,  ATOM_FDIM, 5  * 2048);
    cvt_w<<<(16 * 2048 + 255) / 256, 256, 0, stream>>>(W_h,  Wh1T, HIDDEN,    16 * 2048);
    cvt_w<<<(5  * 2048 + 255) / 256, 256, 0, stream>>>(W_o,  Wo1T, ATOM_FDIM, 5  * 2048);
    cvt_w<<<(16 * 2048 + 255) / 256, 256, 0, stream>>>(W_o + (size_t)ATOM_FDIM * HIDDEN,
                                                       Wo2T, HIDDEN, 16 * 2048);

    // c_b (bond@Wh2) -> baseB
    cb_k<<<gA, 256, 0, stream>>>(f_bonds, a2b, Wh2f, baseB, M);
    // EPI0: acc = atomf@Wi; baseB += acc; msgQA = quant(relu(acc))
    mfma_gemm<0, false, true><<<gG, 512, 0, stream>>>(
        nullptr, nullptr, nullptr, nullptr, atomf, WiT,
        nullptr, nullptr, nullptr, baseB, msgQA, scaleA, M);
    // 3 iters: msg' = quant(relu(g6(msg)@Wh1 + base))
    mfma_gemm<1, true, false><<<gG, 512, 0, stream>>>(
        msgQA, scaleA, a2a, Wh1T, nullptr, nullptr,
        baseB, nullptr, nullptr, nullptr, msgQB, scaleB, M);
    mfma_gemm<1, true, false><<<gG, 512, 0, stream>>>(
        msgQB, scaleB, a2a, Wh1T, nullptr, nullptr,
        baseB, nullptr, nullptr, nullptr, msgQA, scaleA, M);
    mfma_gemm<1, true, false><<<gG, 512, 0, stream>>>(
        msgQA, scaleA, a2a, Wh1T, nullptr, nullptr,
        baseB, nullptr, nullptr, nullptr, msgQB, scaleB, M);
    // hid = relu(g6(msgQB)@Wo2 + atomf@Wo1 + b_o) -> baseB (bf16, reuse)
    mfma_gemm<2, true, true><<<gG, 512, 0, stream>>>(
        msgQB, scaleB, a2a, Wo2T, atomf, Wo1T,
        nullptr, b_o, baseB, nullptr, nullptr, nullptr, M);
    // segment mean + counts (+ fused nz)
    seg_k<<<NM, 512, 0, stream>>>(baseB, atomf, mol_ids, out, M, NM);
}